// Round 6
// baseline (264.704 us; speedup 1.0000x reference)
//
#include <hip/hip_runtime.h>
#include <hip/hip_bf16.h>

#define VQ_D   64
#define VQ_K   1024
#define ROWS_PER_BLOCK 128           // 4 waves x 32 rows
#define EPS    0.015f

typedef __attribute__((ext_vector_type(8))) short short8_t;
typedef __attribute__((ext_vector_type(4))) float f32x4;

static __device__ __forceinline__ short f2bf_s(float f) {
    __hip_bfloat16 b = __float2bfloat16(f);
    short s; __builtin_memcpy(&s, &b, 2); return s;
}
static __device__ __forceinline__ float bf2f(short s) {
    __hip_bfloat16 b; __builtin_memcpy(&b, &s, 2); return __bfloat162float(b);
}

// ---------------- kernel 0: swizzle w into per-lane MFMA fragment order + wsq
// wS layout: chunk T = 16 codes (T = c>>4, 64 chunks) = 2048 shorts:
//   sub 0: hi K-half 0, sub 1: hi K-half 1, sub 2: lo K-half 0, sub 3: lo K-half 1
//   within sub: slot (q*16 + l) * 8 shorts  (q = k-quad, l = code mod 16)
__global__ __launch_bounds__(256) void vq_prep_kernel(
    const float* __restrict__ w, short* __restrict__ wS,
    float* __restrict__ wsq_g, float* __restrict__ wsqm_g,
    int* __restrict__ counter) {
    const int c = blockIdx.x * 256 + threadIdx.x;   // code id; grid = K/256
    if (c == 0) *counter = 0;
    if (c >= VQ_K) return;
    const int T = c >> 4, l = c & 15;
    short* tbase = wS + (size_t)T * 2048;
    float sx = 0.f, sy = 0.f, sz = 0.f, sw = 0.f;
#pragma unroll
    for (int b = 0; b < 2; ++b)
#pragma unroll
        for (int q = 0; q < 4; ++q) {
            const float* src = w + (size_t)c * VQ_D + b * 32 + q * 8;
            f32x4 v0 = *reinterpret_cast<const f32x4*>(src);
            f32x4 v1 = *reinterpret_cast<const f32x4*>(src + 4);
            float vv[8] = {v0[0], v0[1], v0[2], v0[3], v1[0], v1[1], v1[2], v1[3]};
            short8_t hs, ls;
#pragma unroll
            for (int j = 0; j < 8; ++j) {
                short h = f2bf_s(vv[j]);
                hs[j] = h;
                ls[j] = f2bf_s(vv[j] - bf2f(h));
            }
            *reinterpret_cast<short8_t*>(tbase + b * 512 + (q * 16 + l) * 8) = hs;
            *reinterpret_cast<short8_t*>(tbase + 1024 + b * 512 + (q * 16 + l) * 8) = ls;
            // wsq in EXACT round-2 partial order (f32x4 ascending, 4 chains)
            sx = fmaf(v0[0], v0[0], sx); sy = fmaf(v0[1], v0[1], sy);
            sz = fmaf(v0[2], v0[2], sz); sw = fmaf(v0[3], v0[3], sw);
            sx = fmaf(v1[0], v1[0], sx); sy = fmaf(v1[1], v1[1], sy);
            sz = fmaf(v1[2], v1[2], sz); sw = fmaf(v1[3], v1[3], sw);
        }
    float s = (sx + sy) + (sz + sw);
    wsq_g[c]  = s;            // exact, for fix kernel
    wsqm_g[c] = -0.5f * s;    // MFMA C-bias: argmax(dot - wsq/2) == argmin(wsq - 2dot)
}

// ---------------- kernel 1: barrier-free MFMA scores, top-2, outputs
// rt=2 (32 rows/wave): ~50 fewer live VGPRs than rt=4 -> target 5 waves/SIMD.
__global__ __launch_bounds__(256) void vq_main_kernel(
    const float* __restrict__ x, const short* __restrict__ wS,
    const float* __restrict__ wsqm_g, const float* __restrict__ w,
    float* __restrict__ qout, float* __restrict__ iout,
    int* __restrict__ counter, int* __restrict__ list, int cap) {

    __shared__ float wsqm[VQ_K];          // 4 KB
    __shared__ int   idxL[ROWS_PER_BLOCK];
    __shared__ float gapL[ROWS_PER_BLOCK];

    const int t    = threadIdx.x;
    const int wid  = t >> 6;
    const int lane = t & 63;
    const int quad = lane >> 4;
    const int ln15 = lane & 15;
    const long long rowBase = (long long)blockIdx.x * ROWS_PER_BLOCK;

    // ---- stage wsqm (block-shared, one barrier total)
#pragma unroll
    for (int i = 0; i < 4; ++i) wsqm[i * 256 + t] = wsqm_g[i * 256 + t];

    // ---- A fragments straight from global x (hi/lo bf16 split)
    short8_t ah[2][2], al[2][2];
#pragma unroll
    for (int rt = 0; rt < 2; ++rt)
#pragma unroll
        for (int ks = 0; ks < 2; ++ks) {
            const float* xp = x + (rowBase + wid * 32 + rt * 16 + ln15) * VQ_D + ks * 32 + quad * 8;
            f32x4 v0 = *reinterpret_cast<const f32x4*>(xp);
            f32x4 v1 = *reinterpret_cast<const f32x4*>(xp + 4);
            float vv[8] = {v0[0], v0[1], v0[2], v0[3], v1[0], v1[1], v1[2], v1[3]};
#pragma unroll
            for (int j = 0; j < 8; ++j) {
                short h = f2bf_s(vv[j]);
                ah[rt][ks][j] = h;
                al[rt][ks][j] = f2bf_s(vv[j] - bf2f(h));
            }
        }

    float m1[2][4], m2[2][4]; int i1[2][4];
#pragma unroll
    for (int rt = 0; rt < 2; ++rt)
#pragma unroll
        for (int r = 0; r < 4; ++r) {
            m1[rt][r] = -3.402823466e38f; m2[rt][r] = -3.402823466e38f; i1[rt][r] = 0;
        }

    __syncthreads();   // wsqm ready (the ONLY hot-path barrier)

    const int laneoff = lane * 8;     // shorts
    for (int kt = 0; kt < VQ_K / 64; ++kt) {
#pragma unroll
        for (int ct = 0; ct < 4; ++ct) {
            const short* cb = wS + (size_t)(kt * 4 + ct) * 2048 + laneoff;
            short8_t bh0 = *reinterpret_cast<const short8_t*>(cb);
            short8_t bh1 = *reinterpret_cast<const short8_t*>(cb + 512);
            short8_t bl0 = *reinterpret_cast<const short8_t*>(cb + 1024);
            short8_t bl1 = *reinterpret_cast<const short8_t*>(cb + 1536);
            const int   kc = kt * 64 + ct * 16 + ln15;
            const float wm = wsqm[kc];     // 16 banks, broadcast: conflict-free
#pragma unroll
            for (int rt = 0; rt < 2; ++rt) {
                f32x4 acc = {wm, wm, wm, wm};   // C-bias: acc = dot - wsq/2
                acc = __builtin_amdgcn_mfma_f32_16x16x32_bf16(ah[rt][0], bh0, acc, 0, 0, 0);
                acc = __builtin_amdgcn_mfma_f32_16x16x32_bf16(al[rt][0], bh0, acc, 0, 0, 0);
                acc = __builtin_amdgcn_mfma_f32_16x16x32_bf16(ah[rt][0], bl0, acc, 0, 0, 0);
                acc = __builtin_amdgcn_mfma_f32_16x16x32_bf16(ah[rt][1], bh1, acc, 0, 0, 0);
                acc = __builtin_amdgcn_mfma_f32_16x16x32_bf16(al[rt][1], bh1, acc, 0, 0, 0);
                acc = __builtin_amdgcn_mfma_f32_16x16x32_bf16(ah[rt][1], bl1, acc, 0, 0, 0);
#pragma unroll
                for (int r = 0; r < 4; ++r) {
                    float s = acc[r];                                  // maximize
                    bool gt = s > m1[rt][r];
                    m2[rt][r] = fmaxf(m2[rt][r], fminf(s, m1[rt][r]));
                    i1[rt][r] = gt ? kc : i1[rt][r];
                    m1[rt][r] = fmaxf(m1[rt][r], s);
                }
            }
        }
    }

    // ---- cross-lane top-2 merge within each 16-lane group (no tie logic:
    //      any near-tie has gap < EPS -> flagged -> exact fix resolves it)
#pragma unroll
    for (int rt = 0; rt < 2; ++rt)
#pragma unroll
        for (int r = 0; r < 4; ++r) {
            float a1 = m1[rt][r]; int ai = i1[rt][r]; float a2 = m2[rt][r];
#pragma unroll
            for (int mask = 1; mask < 16; mask <<= 1) {
                float b1 = __shfl_xor(a1, mask, 64);
                int   bi = __shfl_xor(ai, mask, 64);
                float b2 = __shfl_xor(a2, mask, 64);
                float n2 = fmaxf(fmaxf(a2, b2), fminf(a1, b1));
                if (b1 > a1) { a1 = b1; ai = bi; }
                a2 = n2;
            }
            if (ln15 == 0) {
                int row = wid * 32 + rt * 16 + quad * 4 + r;
                idxL[row] = ai;
                gapL[row] = 2.0f * (a1 - a2);    // score-space gap
            }
        }
    __syncthreads();

    // ---- outputs
    if (t < ROWS_PER_BLOCK) {
        iout[rowBase + t] = (float)idxL[t];
        if (gapL[t] < EPS) {
            int pos = atomicAdd(counter, 1);
            if (pos < cap) list[pos] = (int)(rowBase + t);
        }
    }
#pragma unroll
    for (int it = 0; it < 8; ++it) {
        int cid = it * 256 + t;            // 2048 float4 chunks
        int row = cid >> 4, seg = cid & 15;
        int idx = idxL[row];
        reinterpret_cast<f32x4*>(qout + (rowBase + row) * VQ_D)[seg] =
            reinterpret_cast<const f32x4*>(w + (size_t)idx * VQ_D)[seg];
    }
}

// ---------------- kernel 2: exact fp32 re-solve, wave per row, shuffle-only
__global__ __launch_bounds__(256) void vq_fix_kernel(
    const float* __restrict__ x, const float* __restrict__ w,
    const float* __restrict__ wsq_g,
    const int* __restrict__ counter, const int* __restrict__ list, int cap,
    float* __restrict__ qout, float* __restrict__ iout, int N) {

    const int lane   = threadIdx.x & 63;
    const int waveId = (blockIdx.x * 256 + threadIdx.x) >> 6;
    const int nWaves = (gridDim.x * 256) >> 6;

    int cnt = *counter;
    bool ovf = cnt > cap;
    int nwork = ovf ? N : cnt;

    for (int i = waveId; i < nwork; i += nWaves) {
        int row = ovf ? i : list[i];

        // every lane holds the full x row (broadcast loads, L1-served)
        f32x4 xv[16];
#pragma unroll
        for (int j = 0; j < 16; ++j)
            xv[j] = reinterpret_cast<const f32x4*>(x + (size_t)row * VQ_D)[j];
        float sx = 0.f, sy = 0.f, sz = 0.f, sw = 0.f;
#pragma unroll
        for (int j = 0; j < 16; ++j) {
            sx = fmaf(xv[j][0], xv[j][0], sx); sy = fmaf(xv[j][1], xv[j][1], sy);
            sz = fmaf(xv[j][2], xv[j][2], sz); sw = fmaf(xv[j][3], xv[j][3], sw);
        }
        float xsq = (sx + sy) + (sz + sw);

        float bm = 3.402823466e38f; int bk = 0x7fffffff;
#pragma unroll 2
        for (int c = 0; c < 16; ++c) {
            int k = c * 64 + lane;                  // ascending per lane
            const f32x4* wr = reinterpret_cast<const f32x4*>(w + (size_t)k * VQ_D);
            float ax = 0.f, ay = 0.f, az = 0.f, aw = 0.f;
#pragma unroll
            for (int j = 0; j < 16; ++j) {
                f32x4 v = wr[j];
                ax = fmaf(xv[j][0], v[0], ax); ay = fmaf(xv[j][1], v[1], ay);
                az = fmaf(xv[j][2], v[2], az); aw = fmaf(xv[j][3], v[3], aw);
            }
            float dot = (ax + ay) + (az + aw);
            float s = (xsq - 2.0f * dot) + wsq_g[k];   // bit-identical round-2 chain
            if (s < bm) { bm = s; bk = k; }
        }
        // wave reduce (min value, smallest k on ties)
#pragma unroll
        for (int mask = 1; mask < 64; mask <<= 1) {
            float om = __shfl_xor(bm, mask, 64);
            int   ok = __shfl_xor(bk, mask, 64);
            if (om < bm || (om == bm && ok < bk)) { bm = om; bk = ok; }
        }
        if (lane == 0) iout[row] = (float)bk;
        if (lane < 16)
            reinterpret_cast<f32x4*>(qout + (size_t)row * VQ_D)[lane] =
                reinterpret_cast<const f32x4*>(w + (size_t)bk * VQ_D)[lane];
    }
}

extern "C" void kernel_launch(void* const* d_in, const int* in_sizes, int n_in,
                              void* d_out, int out_size, void* d_ws, size_t ws_size,
                              hipStream_t stream) {
    const float* x = (const float*)d_in[0];
    const float* w = (const float*)d_in[1];
    const int N = in_sizes[0] / VQ_D;      // 262144

    float* qout = (float*)d_out;
    float* iout = qout + (size_t)N * VQ_D;

    // workspace layout
    char* ws = (char*)d_ws;
    short* wS      = (short*)(ws);                   // 256 KiB swizzled hi/lo codebook
    float* wsq_g   = (float*)(ws + 262144);          // 4 KiB exact ||w||^2
    float* wsqm_g  = (float*)(ws + 266240);          // 4 KiB  -||w||^2/2 (MFMA bias)
    int*   counter = (int*)(ws + 270336);            // 4 B
    int*   list    = (int*)(ws + 270340);
    long long capLL = ((long long)ws_size - 270340) / 4;
    int cap = capLL < 0 ? 0 : (capLL > N ? N : (int)capLL);

    vq_prep_kernel<<<VQ_K / 256, 256, 0, stream>>>(w, wS, wsq_g, wsqm_g, counter);
    vq_main_kernel<<<N / ROWS_PER_BLOCK, 256, 0, stream>>>(
        x, wS, wsqm_g, w, qout, iout, counter, list, cap);
    vq_fix_kernel<<<1024, 256, 0, stream>>>(x, w, wsq_g, counter, list, cap, qout, iout, N);
}